// Round 1
// baseline (1151.262 us; speedup 1.0000x reference)
//
#include <hip/hip_runtime.h>
#include <cstdint>

// LaplaceNet: 20 Jacobi sweeps on 4096^2 fp32 grid.
// packed field trick: sign bit = boundary flag; magnitude = Cc (interior) or bc (boundary).
// Buffers: out1 = V ping (final lands here), out2 = packed (overwritten with C_pos at end),
//          ws   = V pong (64 MB needed).

#define RES 4096
#define N_CELLS (RES * RES)

// ---------------- Kernel A: precompute packed field + V0 -----------------
// 32x32 output tile per block; 11x11 box filter done separably in LDS (halo 5).
__global__ __launch_bounds__(1024) void lap_precompute(
    const float* __restrict__ x, const float* __restrict__ bt,
    const float* __restrict__ bc, const float* __restrict__ C,
    float* __restrict__ V0, uint32_t* __restrict__ packed)
{
    __shared__ float ob[42][42];    // objects_bounds tile incl halo 5
    __shared__ float hsum[42][32];  // horizontal 11-sum
    const int tx = threadIdx.x, ty = threadIdx.y;
    const int t = ty * 32 + tx;
    const int br = blockIdx.y * 32, bcol = blockIdx.x * 32;

    // load 42x42 objects_bounds tile (zero outside image — conv 'SAME' zero-pads)
    for (int idx = t; idx < 42 * 42; idx += 1024) {
        int r = idx / 42, c = idx % 42;
        int gr = br + r - 5, gc = bcol + c - 5;
        float v = 0.f;
        if (gr >= 0 && gr < RES && gc >= 0 && gc < RES) {
            int g = gr * RES + gc;
            float btv = bt[g], bcv = bc[g];
            v = (btv == 1.0f && bcv > 0.f) ? bcv : 0.f;
        }
        ob[r][c] = v;
    }
    __syncthreads();

    // horizontal pass: hsum[r][c] = sum_{d=0..10} ob[r][c+d]  (center = c+5)
    for (int idx = t; idx < 42 * 32; idx += 1024) {
        int r = idx / 32, c = idx % 32;
        float s = 0.f;
#pragma unroll
        for (int d = 0; d < 11; ++d) s += ob[r][c + d];
        hsum[r][c] = s;
    }
    __syncthreads();

    // vertical pass + per-cell pack
    const int gr = br + ty, gc = bcol + tx;
    const int g = gr * RES + gc;
    float vs = 0.f;
#pragma unroll
    for (int d = 0; d < 11; ++d) vs += hsum[ty + d][tx];

    const float btv = bt[g];
    const float bcv = bc[g];
    const float cpos = fmaxf(C[g], 0.f);
    const bool interior = (btv == 0.0f);
    const float Cc = cpos + vs * (1.0f / 121.0f);  // extra masked to interior below
    uint32_t pk;
    if (interior) pk = __float_as_uint(Cc);                    // sign bit 0 (Cc >= 0)
    else          pk = __float_as_uint(bcv) | 0x80000000u;     // flag boundary
    packed[g] = pk;
    V0[g] = interior ? x[g] : bcv;
}

// ---------------- Kernel B: one Jacobi sweep (float4 per thread) ----------
__device__ __forceinline__ float lap_cell(uint32_t pk, float up, float dn, float lf, float rt)
{
    if (pk >> 31) return __uint_as_float(pk & 0x7fffffffu);           // boundary: bc
    return 0.25f * (up + dn + lf + rt) + __uint_as_float(pk);          // interior: avg + Cc
}

__global__ __launch_bounds__(256) void lap_jacobi(
    const float* __restrict__ Vin, const uint32_t* __restrict__ packed,
    float* __restrict__ Vout)
{
    const int i  = blockIdx.y;
    const int j4 = (blockIdx.x * 256 + threadIdx.x) * 4;
    const int idx = i * RES + j4;

    const float4 ctr = *(const float4*)(Vin + idx);
    const int iu = (i > 0)       ? i - 1 : 0;        // edge replicate
    const int id = (i < RES - 1) ? i + 1 : i;
    const float4 up = *(const float4*)(Vin + iu * RES + j4);
    const float4 dn = *(const float4*)(Vin + id * RES + j4);
    const float lf = (j4 > 0)         ? Vin[idx - 1] : ctr.x;
    const float rt = (j4 + 4 < RES)   ? Vin[idx + 4] : ctr.w;
    const uint4 pk = *(const uint4*)(packed + idx);

    float4 o;
    o.x = lap_cell(pk.x, up.x, dn.x, lf,    ctr.y);
    o.y = lap_cell(pk.y, up.y, dn.y, ctr.x, ctr.z);
    o.z = lap_cell(pk.z, up.z, dn.z, ctr.y, ctr.w);
    o.w = lap_cell(pk.w, up.w, dn.w, ctr.z, rt);
    *(float4*)(Vout + idx) = o;
}

// ---------------- Kernel C: final sweep fused with output transform -------
__global__ __launch_bounds__(256) void lap_jacobi_final(
    const float* __restrict__ Vin, const uint32_t* __restrict__ packed,
    float* __restrict__ Out)
{
    const int i  = blockIdx.y;
    const int j4 = (blockIdx.x * 256 + threadIdx.x) * 4;
    const int idx = i * RES + j4;

    const float4 ctr = *(const float4*)(Vin + idx);
    const int iu = (i > 0)       ? i - 1 : 0;
    const int id = (i < RES - 1) ? i + 1 : i;
    const float4 up = *(const float4*)(Vin + iu * RES + j4);
    const float4 dn = *(const float4*)(Vin + id * RES + j4);
    const float lf = (j4 > 0)       ? Vin[idx - 1] : ctr.x;
    const float rt = (j4 + 4 < RES) ? Vin[idx + 4] : ctr.w;
    const uint4 pk = *(const uint4*)(packed + idx);

    float4 o;
    float v;
    v = lap_cell(pk.x, up.x, dn.x, lf,    ctr.y); o.x = (pk.x >> 31) ? v : (v >= 1.0f ? 0.95f : v);
    v = lap_cell(pk.y, up.y, dn.y, ctr.x, ctr.z); o.y = (pk.y >> 31) ? v : (v >= 1.0f ? 0.95f : v);
    v = lap_cell(pk.z, up.z, dn.z, ctr.y, ctr.w); o.z = (pk.z >> 31) ? v : (v >= 1.0f ? 0.95f : v);
    v = lap_cell(pk.w, up.w, dn.w, ctr.z, rt);    o.w = (pk.w >> 31) ? v : (v >= 1.0f ? 0.95f : v);
    *(float4*)(Out + idx) = o;
}

// ---------------- Kernel D: C_pos output (overwrites packed region) -------
__global__ __launch_bounds__(256) void lap_cpos(
    const float* __restrict__ C, float* __restrict__ out2)
{
    const int idx = (blockIdx.x * 256 + threadIdx.x) * 4;
    const float4 c = *(const float4*)(C + idx);
    float4 o;
    o.x = fmaxf(c.x, 0.f); o.y = fmaxf(c.y, 0.f);
    o.z = fmaxf(c.z, 0.f); o.w = fmaxf(c.w, 0.f);
    *(float4*)(out2 + idx) = o;
}

extern "C" void kernel_launch(void* const* d_in, const int* in_sizes, int n_in,
                              void* d_out, int out_size, void* d_ws, size_t ws_size,
                              hipStream_t stream) {
    const float* x  = (const float*)d_in[0];
    const float* bt = (const float*)d_in[1];
    const float* bc = (const float*)d_in[2];
    const float* C  = (const float*)d_in[3];

    float*     out1   = (float*)d_out;                       // V ping buffer / final out
    uint32_t*  packed = (uint32_t*)((float*)d_out + N_CELLS);// packed field (temporarily)
    float*     vb     = (float*)d_ws;                        // V pong buffer (64 MB)

    // A: precompute packed + V0 (into out1)
    dim3 blkA(32, 32), grdA(RES / 32, RES / 32);
    lap_precompute<<<grdA, blkA, 0, stream>>>(x, bt, bc, C, out1, packed);

    // B: 19 sweeps ping-pong (out1 <-> ws). Sweep k odd -> ws, even -> out1.
    dim3 blkB(256), grdB(RES / 1024, RES);
    float* cur = out1;
    float* nxt = vb;
    for (int it = 0; it < 19; ++it) {
        lap_jacobi<<<grdB, blkB, 0, stream>>>(cur, packed, nxt);
        float* tmp = cur; cur = nxt; nxt = tmp;
    }
    // after 19 sweeps cur == vb; sweep 20 fused with output transform -> out1
    lap_jacobi_final<<<grdB, blkB, 0, stream>>>(cur, packed, out1);

    // D: overwrite packed region with C_pos output
    lap_cpos<<<N_CELLS / 1024, 256, 0, stream>>>(C, (float*)d_out + N_CELLS);
}

// Round 3
// 1134.500 us; speedup vs baseline: 1.0148x; 1.0148x over previous
//
#include <hip/hip_runtime.h>
#include <cstdint>

#define RES 4096
#define N_CELLS (RES*RES)

// ================= fused temporal-blocked Jacobi =================
// 4 launches x 5 steps = 20 sweeps. V in LDS + per-thread regs; packed in regs.
#define T_STEPS 5
#define OW 128
#define OH 64
#define HALO_V 5
#define HALO_H 8                    // >=5 needed; 8 keeps float4 alignment
#define IW (OW + 2*HALO_H)          // 144
#define IH (OH + 2*HALO_V)          // 74
#define NF4 (IW/4)                  // 36
#define NSLOT (NF4*IH)              // 2664
#define NTHR 512
#define NITER ((NSLOT + NTHR - 1)/NTHR)  // 6
#define LDSW 148                    // padded row width in floats (16B-aligned rows)

template<int FINAL>
__global__ __launch_bounds__(NTHR) void lap_fused(
    const float* __restrict__ Vin, const uint32_t* __restrict__ packed,
    float* __restrict__ Vout)
{
    __shared__ float lds[IH * LDSW];   // 43.8 KB
    const int tid = threadIdx.x;
    const int r0 = blockIdx.y * OH;
    const int c0 = blockIdx.x * OW;

    float4 v[NITER];
    uint4  pk[NITER];
    int    gr_[NITER], gc_[NITER], loff[NITER];
    bool   act[NITER];

    // ---- stage: global -> regs + LDS ----
#pragma unroll
    for (int k = 0; k < NITER; ++k) {
        int idx = tid + k * NTHR;
        const bool a = idx < NSLOT;
        act[k] = a;
        if (!a) idx = 0;
        const int lrow  = idx / NF4;
        const int lcol4 = idx - lrow * NF4;
        const int gr = r0 - HALO_V + lrow;
        const int gc = c0 - HALO_H + lcol4 * 4;
        gr_[k] = gr; gc_[k] = gc;
        const int lo = lrow * LDSW + lcol4 * 4;
        loff[k] = lo;
        float4 vv = {0.f,0.f,0.f,0.f}; uint4 pp = {0u,0u,0u,0u};
        if (a) {
            const int rr = gr < 0 ? 0 : (gr > RES-1 ? RES-1 : gr);
            if (gc >= 0 && gc + 3 <= RES-1) {
                vv = *(const float4*)(Vin    + (size_t)rr * RES + gc);
                pp = *(const uint4*) (packed + (size_t)rr * RES + gc);
            } else {
#pragma unroll
                for (int e = 0; e < 4; ++e) {
                    int cc = gc + e; cc = cc < 0 ? 0 : (cc > RES-1 ? RES-1 : cc);
                    ((float*)&vv)[e]    = Vin   [(size_t)rr * RES + cc];
                    ((uint32_t*)&pp)[e] = packed[(size_t)rr * RES + cc];
                }
            }
            *(float4*)(&lds[lo]) = vv;
        }
        v[k] = vv; pk[k] = pp;
    }
    __syncthreads();

    // ---- T_STEPS Jacobi steps on the shrinking pyramid ----
    for (int s = 1; s <= T_STEPS; ++s) {
        const int rlo = (r0 == 0)        ? 0   : (r0 - HALO_V + s);
        const int rhi = (r0 + OH == RES) ? RES : (r0 + OH + HALO_V - s);
        const int clo = (c0 == 0)        ? 0   : (c0 - HALO_H + s);
        const int chi = (c0 + OW == RES) ? RES : (c0 + OW + HALO_H - s);
#pragma unroll
        for (int k = 0; k < NITER; ++k) {
            const int gr = gr_[k], gc = gc_[k];
            if (act[k] && gr >= rlo && gr < rhi) {
                const int lo = loff[k];
                int upo = (gr == 0)     ? lo : lo - LDSW; if (upo < 0) upo = lo;
                int dno = (gr == RES-1) ? lo : lo + LDSW; if (dno > IH*LDSW - 4) dno = lo;
                const float4 up = *(const float4*)(&lds[upo]);
                const float4 dn = *(const float4*)(&lds[dno]);
                int lfo = lo - 1; if (lfo < 0) lfo = 0;
                const float lf = (gc == 0)         ? v[k].x : lds[lfo];
                const float rt = (gc + 3 == RES-1) ? v[k].w : lds[lo + 4];
                float4 nv;
                {   const float m  = __uint_as_float(pk[k].x & 0x7fffffffu);
                    const float av = 0.25f*(up.x + dn.x + lf + v[k].y) + m;
                    nv.x = (pk[k].x >> 31) ? m : av; }
                {   const float m  = __uint_as_float(pk[k].y & 0x7fffffffu);
                    const float av = 0.25f*(up.y + dn.y + v[k].x + v[k].z) + m;
                    nv.y = (pk[k].y >> 31) ? m : av; }
                {   const float m  = __uint_as_float(pk[k].z & 0x7fffffffu);
                    const float av = 0.25f*(up.z + dn.z + v[k].y + v[k].w) + m;
                    nv.z = (pk[k].z >> 31) ? m : av; }
                {   const float m  = __uint_as_float(pk[k].w & 0x7fffffffu);
                    const float av = 0.25f*(up.w + dn.w + v[k].z + rt) + m;
                    nv.w = (pk[k].w >> 31) ? m : av; }
                if (gc + 0 >= clo && gc + 0 < chi) v[k].x = nv.x;
                if (gc + 1 >= clo && gc + 1 < chi) v[k].y = nv.y;
                if (gc + 2 >= clo && gc + 2 < chi) v[k].z = nv.z;
                if (gc + 3 >= clo && gc + 3 < chi) v[k].w = nv.w;
            }
        }
        if (s < T_STEPS) {
            __syncthreads();
#pragma unroll
            for (int k = 0; k < NITER; ++k)
                if (act[k]) *(float4*)(&lds[loff[k]]) = v[k];
            __syncthreads();
        }
    }

    // ---- store output region ----
#pragma unroll
    for (int k = 0; k < NITER; ++k) {
        const int gr = gr_[k], gc = gc_[k];
        if (act[k] && gr >= r0 && gr < r0 + OH && gc >= c0 && gc + 3 < c0 + OW) {
            float4 o = v[k];
            if (FINAL) {
                o.x = (pk[k].x >> 31) ? o.x : (o.x >= 1.0f ? 0.95f : o.x);
                o.y = (pk[k].y >> 31) ? o.y : (o.y >= 1.0f ? 0.95f : o.y);
                o.z = (pk[k].z >> 31) ? o.z : (o.z >= 1.0f ? 0.95f : o.z);
                o.w = (pk[k].w >> 31) ? o.w : (o.w >= 1.0f ? 0.95f : o.w);
            }
            *(float4*)(Vout + (size_t)gr * RES + gc) = o;
        }
    }
}

// ================= precompute: packed field + V0 =================
#define PB_OW 64
#define PB_OH 64
#define PB_HH 8
#define PB_HV 5
#define PB_IW (PB_OW + 2*PB_HH)   // 80
#define PB_IH (PB_OH + 2*PB_HV)   // 74
#define PB_NF4 (PB_IW/4)          // 20
#define PB_NSLOT (PB_NF4*PB_IH)   // 1480
#define PB_THR 256
#define PB_LDSW 84
#define PB_HLDSW 68

__global__ __launch_bounds__(PB_THR) void lap_precompute(
    const float* __restrict__ x, const float* __restrict__ bt,
    const float* __restrict__ bc, const float* __restrict__ C,
    float* __restrict__ V0, uint32_t* __restrict__ packed)
{
    __shared__ float ob[PB_IH * PB_LDSW];   // 24.9 KB
    __shared__ float hs[PB_IH * PB_HLDSW];  // 20.1 KB
    const int tid = threadIdx.x;
    const int r0 = blockIdx.y * PB_OH, c0 = blockIdx.x * PB_OW;

    // objects_bounds tile (zero outside image — conv 'SAME' zero-pads)
    for (int idx = tid; idx < PB_NSLOT; idx += PB_THR) {
        const int lrow = idx / PB_NF4;
        const int lcol4 = idx - lrow * PB_NF4;
        const int gr = r0 - PB_HV + lrow;
        const int gc = c0 - PB_HH + lcol4 * 4;
        float4 o = {0.f,0.f,0.f,0.f};
        if (gr >= 0 && gr < RES) {
            if (gc >= 0 && gc + 3 < RES) {
                const float4 b = *(const float4*)(bt + (size_t)gr*RES + gc);
                const float4 w = *(const float4*)(bc + (size_t)gr*RES + gc);
                o.x = (b.x == 1.f && w.x > 0.f) ? w.x : 0.f;
                o.y = (b.y == 1.f && w.y > 0.f) ? w.y : 0.f;
                o.z = (b.z == 1.f && w.z > 0.f) ? w.z : 0.f;
                o.w = (b.w == 1.f && w.w > 0.f) ? w.w : 0.f;
            } else {
#pragma unroll
                for (int e = 0; e < 4; ++e) {
                    const int cc = gc + e;
                    if (cc >= 0 && cc < RES) {
                        const float b = bt[(size_t)gr*RES + cc];
                        const float w = bc[(size_t)gr*RES + cc];
                        ((float*)&o)[e] = (b == 1.f && w > 0.f) ? w : 0.f;
                    }
                }
            }
        }
        *(float4*)(&ob[lrow*PB_LDSW + lcol4*4]) = o;
    }
    __syncthreads();

    // horizontal 11-sum: out col j uses ob cols [j+3, j+13]
    for (int idx = tid; idx < PB_IH * 16; idx += PB_THR) {
        const int lrow = idx >> 4;
        const int j4 = (idx & 15) << 2;
        const float* row = &ob[lrow * PB_LDSW];
        const float4 a0 = *(const float4*)(row + j4);
        const float4 a1 = *(const float4*)(row + j4 + 4);
        const float4 a2 = *(const float4*)(row + j4 + 8);
        const float4 a3 = *(const float4*)(row + j4 + 12);
        const float4 a4 = *(const float4*)(row + j4 + 16);
        const float common = a1.z + a1.w + a2.x + a2.y + a2.z + a2.w + a3.x + a3.y;
        float4 s;
        s.x = common + a0.w + a1.x + a1.y;
        s.y = common + a1.x + a1.y + a3.z;
        s.z = common + a1.y + a3.z + a3.w;
        s.w = common + a3.z + a3.w + a4.x;
        *(float4*)(&hs[lrow * PB_HLDSW + j4]) = s;
    }
    __syncthreads();

    // vertical 11-sum + pack + V0
    for (int idx = tid; idx < PB_OH * 16; idx += PB_THR) {
        const int i = idx >> 4;
        const int j4 = (idx & 15) << 2;
        float sx=0.f, sy=0.f, sz=0.f, sw=0.f;
#pragma unroll
        for (int d = 0; d < 11; ++d) {
            const float4 h = *(const float4*)(&hs[(i + d) * PB_HLDSW + j4]);
            sx += h.x; sy += h.y; sz += h.z; sw += h.w;
        }
        const int gr = r0 + i, gc = c0 + j4;
        const size_t g = (size_t)gr * RES + gc;
        const float4 xx  = *(const float4*)(x  + g);
        const float4 cc  = *(const float4*)(C  + g);
        const float4 btv = *(const float4*)(bt + g);
        const float4 bcv = *(const float4*)(bc + g);
        float4 v0; uint4 pko;
        const float es[4] = {sx, sy, sz, sw};
#pragma unroll
        for (int e = 0; e < 4; ++e) {
            const float cpos = fmaxf(((const float*)&cc)[e], 0.f);
            const bool interior = (((const float*)&btv)[e] == 0.0f);
            const float Cc = cpos + es[e] * (1.0f / 121.0f);
            const float bce = ((const float*)&bcv)[e];
            ((uint32_t*)&pko)[e] = interior ? __float_as_uint(Cc)
                                           : (__float_as_uint(bce) | 0x80000000u);
            ((float*)&v0)[e] = interior ? ((const float*)&xx)[e] : bce;
        }
        *(uint4*)(packed + g) = pko;
        *(float4*)(V0 + g) = v0;
    }
}

// ================= C_pos output =================
__global__ __launch_bounds__(256) void lap_cpos(
    const float* __restrict__ C, float* __restrict__ out2)
{
    const int idx = (blockIdx.x * 256 + threadIdx.x) * 4;
    const float4 c = *(const float4*)(C + idx);
    float4 o;
    o.x = fmaxf(c.x, 0.f); o.y = fmaxf(c.y, 0.f);
    o.z = fmaxf(c.z, 0.f); o.w = fmaxf(c.w, 0.f);
    *(float4*)(out2 + idx) = o;
}

extern "C" void kernel_launch(void* const* d_in, const int* in_sizes, int n_in,
                              void* d_out, int out_size, void* d_ws, size_t ws_size,
                              hipStream_t stream) {
    const float* x  = (const float*)d_in[0];
    const float* bt = (const float*)d_in[1];
    const float* bc = (const float*)d_in[2];
    const float* C  = (const float*)d_in[3];

    float*    out1   = (float*)d_out;                        // V ping / final out
    uint32_t* packed = (uint32_t*)((float*)d_out + N_CELLS); // packed field (until cpos)
    float*    vb     = (float*)d_ws;                         // V pong (64 MB)

    dim3 gP(RES / PB_OW, RES / PB_OH);
    lap_precompute<<<gP, PB_THR, 0, stream>>>(x, bt, bc, C, out1, packed);

    dim3 gF(RES / OW, RES / OH);   // 32 x 64
    lap_fused<0><<<gF, NTHR, 0, stream>>>(out1, packed, vb);
    lap_fused<0><<<gF, NTHR, 0, stream>>>(vb,   packed, out1);
    lap_fused<0><<<gF, NTHR, 0, stream>>>(out1, packed, vb);
    lap_fused<1><<<gF, NTHR, 0, stream>>>(vb,   packed, out1);

    lap_cpos<<<N_CELLS / 1024, 256, 0, stream>>>(C, (float*)d_out + N_CELLS);
}